// Round 7
// baseline (280.520 us; speedup 1.0000x reference)
//
#include <hip/hip_runtime.h>

#define N_NODES 50000
#define N_EDGES 600000
#define N_PAD 50048        // N rounded up to 64 (mlp tiles)
#define IN_CH 64
#define HID 128
#define N_GRAPHS 64
#define CAP 64             // per-node edge-slot capacity (max degree ~28 for this input)
#define CAP_SHIFT 6

typedef __attribute__((ext_vector_type(8))) short bf16x8;
typedef __attribute__((ext_vector_type(4))) float f32x4;

// ---- bf16 helpers (manual, RNE) ----
__device__ __forceinline__ float bf2f(unsigned short u) {
    union { unsigned int i; float f; } v; v.i = ((unsigned int)u) << 16; return v.f;
}
__device__ __forceinline__ unsigned short f2bf(float f) {
    union { float f; unsigned int i; } v; v.f = f;
    unsigned int u = v.i;
    return (unsigned short)((u + 0x7FFFu + ((u >> 16) & 1u)) >> 16);
}

// 8B edge record: x = src(u16) | a0(bf16)<<16 ; y = a1(bf16) | a2(bf16)<<16

// ===========================================================================
// prep kernel: zero deg + OUT, 4 weight transposes, x->bf16, inv_cnt[64]
// (R6-proven).
// ===========================================================================
__global__ void prep_kernel(const float* __restrict__ x,
                            const float* __restrict__ w1a, const float* __restrict__ w1b,
                            const float* __restrict__ w2a, const float* __restrict__ w2b,
                            const int* __restrict__ batch,
                            unsigned short* __restrict__ xbf,
                            unsigned short* __restrict__ waT1, unsigned short* __restrict__ wbT1,
                            unsigned short* __restrict__ waT2, unsigned short* __restrict__ wbT2,
                            int* __restrict__ deg, float* __restrict__ out,
                            float* __restrict__ inv_cnt) {
    int i = blockIdx.x * blockDim.x + threadIdx.x;
    if (i < N_NODES * IN_CH) xbf[i] = f2bf(x[i]);
    if (i < N_NODES) deg[i] = 0;
    if (i < N_GRAPHS * HID) out[i] = 0.f;
    if (i < N_GRAPHS) {                  // per-graph 1/count (sorted batch)
        int g = i;
        int lo = 0, hi = N_NODES;
        while (lo < hi) { int mid = (lo + hi) >> 1; if (batch[mid] < g) lo = mid + 1; else hi = mid; }
        int start = lo;
        lo = 0; hi = N_NODES;
        while (lo < hi) { int mid = (lo + hi) >> 1; if (batch[mid] <= g) lo = mid + 1; else hi = mid; }
        float c = (float)(lo - start);
        inv_cnt[g] = 1.0f / (c > 1.0f ? c : 1.0f);
    }
    if (i < IN_CH * HID) {               // w1a is [64,128]
        int k = i / HID, n = i % HID;
        waT1[n * IN_CH + k] = f2bf(w1a[i]);
    }
    if (i < HID * HID) {                 // the three [128,128] weights
        int k = i / HID, n = i % HID;
        wbT1[n * HID + k] = f2bf(w1b[i]);
        waT2[n * HID + k] = f2bf(w2a[i]);
        wbT2[n * HID + k] = f2bf(w2b[i]);
    }
}

// ===========================================================================
// Single-pass edge build: 1 edge/thread, fixed-capacity buckets (R2-proven).
// ===========================================================================
__global__ void build_kernel(const int* __restrict__ ei,
                             const float* __restrict__ ea,
                             int* __restrict__ deg,
                             uint2* __restrict__ edata) {
    int i = blockIdx.x * blockDim.x + threadIdx.x;
    if (i >= N_EDGES) return;
    int s = ei[i];
    int d = ei[N_EDGES + i];
    float a0 = ea[3 * (size_t)i], a1 = ea[3 * (size_t)i + 1], a2 = ea[3 * (size_t)i + 2];
    int p = atomicAdd(&deg[d], 1);
    if (p < CAP)
        edata[((size_t)d << CAP_SHIFT) + p] =
            make_uint2((unsigned)s | ((unsigned)f2bf(a0) << 16),
                       (unsigned)f2bf(a1) | ((unsigned)f2bf(a2) << 16));
}

// ===========================================================================
// R7 gather64: EDGE-PARALLEL lane map. Wave = 16 channel-groups (4 ch each,
// 8B row chunk) x 4 edge slots -> one row-gather instruction fetches 4
// DIFFERENT src rows (4x outstanding loads/wave at flat VGPR). Slot partials
// combined per node via 2 shfl_xor. 1 node/wave.
// ===========================================================================
__global__ __launch_bounds__(256)
void gather64_kernel(const unsigned short* __restrict__ xin,  // bf16 [N,64]
                     const uint2* __restrict__ edata,
                     const int* __restrict__ deg,
                     const float* __restrict__ elw,  // [3, 64]
                     const float* __restrict__ elb,  // [64]
                     unsigned short* __restrict__ sg) {  // bf16 [N, 64]
    const int t = threadIdx.x;
    const int w = t >> 6, l = t & 63;
    const int s = l >> 4;            // edge slot 0..3
    const int c = 4 * (l & 15);      // channel base (4 channels/lane)
    const int node = blockIdx.x * 4 + w;

    const float4 w0 = *(const float4*)&elw[c];
    const float4 w1 = *(const float4*)&elw[64 + c];
    const float4 w2 = *(const float4*)&elw[128 + c];
    const float4 eb = *(const float4*)&elb[c];

    float a0 = 0.f, a1 = 0.f, a2 = 0.f, a3 = 0.f;
    int dn = deg[node]; if (dn > CAP) dn = CAP;
    const int base = node << CAP_SHIFT;
    for (int j0 = 0; j0 < dn; j0 += 4) {
        uint2 e = edata[base + j0 + s];        // slot always within 64-slot bucket
        bool valid = (j0 + s) < dn;
        unsigned src = valid ? (e.x & 0xFFFFu) : 0u;
        float A0 = bf2f((unsigned short)(e.x >> 16));
        float A1 = bf2f((unsigned short)(e.y & 0xFFFF));
        float A2 = bf2f((unsigned short)(e.y >> 16));
        uint2 r = *(const uint2*)&xin[(size_t)src * 64 + c];
        float m0 = bf2f((unsigned short)(r.x & 0xFFFF)) + A0 * w0.x + A1 * w1.x + A2 * w2.x + eb.x;
        float m1 = bf2f((unsigned short)(r.x >> 16))    + A0 * w0.y + A1 * w1.y + A2 * w2.y + eb.y;
        float m2 = bf2f((unsigned short)(r.y & 0xFFFF)) + A0 * w0.z + A1 * w1.z + A2 * w2.z + eb.z;
        float m3 = bf2f((unsigned short)(r.y >> 16))    + A0 * w0.w + A1 * w1.w + A2 * w2.w + eb.w;
        m0 = m0 > 0.f ? m0 : 0.f;  m1 = m1 > 0.f ? m1 : 0.f;
        m2 = m2 > 0.f ? m2 : 0.f;  m3 = m3 > 0.f ? m3 : 0.f;
        a0 += valid ? m0 : 0.f;  a1 += valid ? m1 : 0.f;
        a2 += valid ? m2 : 0.f;  a3 += valid ? m3 : 0.f;
    }
    // combine the 4 edge slots (lanes l, l^16, l^32, l^48 share channels)
    a0 += __shfl_xor(a0, 16); a0 += __shfl_xor(a0, 32);
    a1 += __shfl_xor(a1, 16); a1 += __shfl_xor(a1, 32);
    a2 += __shfl_xor(a2, 16); a2 += __shfl_xor(a2, 32);
    a3 += __shfl_xor(a3, 16); a3 += __shfl_xor(a3, 32);
    if (s == 0) {
        uint2 sv = *(const uint2*)&xin[(size_t)node * 64 + c];   // self row
        a0 += bf2f((unsigned short)(sv.x & 0xFFFF));
        a1 += bf2f((unsigned short)(sv.x >> 16));
        a2 += bf2f((unsigned short)(sv.y & 0xFFFF));
        a3 += bf2f((unsigned short)(sv.y >> 16));
        uint2 o;
        o.x = (unsigned)f2bf(a0) | ((unsigned)f2bf(a1) << 16);
        o.y = (unsigned)f2bf(a2) | ((unsigned)f2bf(a3) << 16);
        *(uint2*)&sg[(size_t)node * 64 + c] = o;
    }
}

// ===========================================================================
// R7 gather128: same edge-parallel map — 32 channel-groups (4 ch) x 2 edge
// slots; 2x outstanding rows/instruction; 1 shfl_xor(32) combine. 1 node/wave.
// ===========================================================================
__global__ __launch_bounds__(256)
void gather128_kernel(const unsigned short* __restrict__ xin,  // bf16 [N,128]
                      const uint2* __restrict__ edata,
                      const int* __restrict__ deg,
                      const float* __restrict__ elw,  // [3, 128]
                      const float* __restrict__ elb,  // [128]
                      unsigned short* __restrict__ sg) {  // bf16 [N, 128]
    const int t = threadIdx.x;
    const int w = t >> 6, l = t & 63;
    const int s = l >> 5;            // edge slot 0..1
    const int c = 4 * (l & 31);      // channel base (4 channels/lane)
    const int node = blockIdx.x * 4 + w;

    const float4 w0 = *(const float4*)&elw[c];
    const float4 w1 = *(const float4*)&elw[HID + c];
    const float4 w2 = *(const float4*)&elw[2 * HID + c];
    const float4 eb = *(const float4*)&elb[c];

    float a0 = 0.f, a1 = 0.f, a2 = 0.f, a3 = 0.f;
    int dn = deg[node]; if (dn > CAP) dn = CAP;
    const int base = node << CAP_SHIFT;
    for (int j0 = 0; j0 < dn; j0 += 2) {
        uint2 e = edata[base + j0 + s];        // slot always within 64-slot bucket
        bool valid = (j0 + s) < dn;
        unsigned src = valid ? (e.x & 0xFFFFu) : 0u;
        float A0 = bf2f((unsigned short)(e.x >> 16));
        float A1 = bf2f((unsigned short)(e.y & 0xFFFF));
        float A2 = bf2f((unsigned short)(e.y >> 16));
        uint2 r = *(const uint2*)&xin[(size_t)src * 128 + c];
        float m0 = bf2f((unsigned short)(r.x & 0xFFFF)) + A0 * w0.x + A1 * w1.x + A2 * w2.x + eb.x;
        float m1 = bf2f((unsigned short)(r.x >> 16))    + A0 * w0.y + A1 * w1.y + A2 * w2.y + eb.y;
        float m2 = bf2f((unsigned short)(r.y & 0xFFFF)) + A0 * w0.z + A1 * w1.z + A2 * w2.z + eb.z;
        float m3 = bf2f((unsigned short)(r.y >> 16))    + A0 * w0.w + A1 * w1.w + A2 * w2.w + eb.w;
        m0 = m0 > 0.f ? m0 : 0.f;  m1 = m1 > 0.f ? m1 : 0.f;
        m2 = m2 > 0.f ? m2 : 0.f;  m3 = m3 > 0.f ? m3 : 0.f;
        a0 += valid ? m0 : 0.f;  a1 += valid ? m1 : 0.f;
        a2 += valid ? m2 : 0.f;  a3 += valid ? m3 : 0.f;
    }
    // combine the 2 edge slots (lanes l and l^32 share channels)
    a0 += __shfl_xor(a0, 32);
    a1 += __shfl_xor(a1, 32);
    a2 += __shfl_xor(a2, 32);
    a3 += __shfl_xor(a3, 32);
    if (s == 0) {
        uint2 sv = *(const uint2*)&xin[(size_t)node * 128 + c];  // self row
        a0 += bf2f((unsigned short)(sv.x & 0xFFFF));
        a1 += bf2f((unsigned short)(sv.x >> 16));
        a2 += bf2f((unsigned short)(sv.y & 0xFFFF));
        a3 += bf2f((unsigned short)(sv.y >> 16));
        uint2 o;
        o.x = (unsigned)f2bf(a0) | ((unsigned)f2bf(a1) << 16);
        o.y = (unsigned)f2bf(a2) | ((unsigned)f2bf(a3) << 16);
        *(uint2*)&sg[(size_t)node * 128 + c] = o;
    }
}

// ===========================================================================
// Standalone MFMA MLP — R12-proven body; R6 fused-mean POOL epilogue.
// ===========================================================================
template <int K, bool POOL>
__global__ __launch_bounds__(256)
void mlp_mfma_kernel(const unsigned short* __restrict__ sg,   // bf16 [N_PAD, K]
                     const unsigned short* __restrict__ waT,  // bf16 [HID, K]
                     const float* __restrict__ ba,
                     const unsigned short* __restrict__ wbT,  // bf16 [HID, HID]
                     const float* __restrict__ bb,
                     void* __restrict__ outv,                 // bf16 h or f32 out
                     const int* __restrict__ batch,
                     const float* __restrict__ inv_cnt) {
    constexpr int HSTR = 136;      // shorts
    constexpr int OSTR = HID + 4;  // f32
    __shared__ __align__(16) unsigned short sHid[4][16 * HSTR];  // 17.4 KB
    __shared__ __align__(16) float sOut[64 * OSTR];              // 33.8 KB
    const int t = threadIdx.x;
    const int w = t >> 6, l = t & 63;
    const int i16 = l & 15, q = l >> 4;
    const int blk0 = blockIdx.x * 64;
    const int row0 = blk0 + w * 16;   // this wave's 16 rows

    // ---- layer A: [16 x K] @ waT -> relu -> own LDS buffer ----
    bf16x8 aA[K / 32];
    #pragma unroll
    for (int s = 0; s < K / 32; s++)
        aA[s] = *(const bf16x8*)&sg[(size_t)(row0 + i16) * K + s * 32 + q * 8];
    unsigned short* myHid = sHid[w];
    #pragma unroll
    for (int ct = 0; ct < 8; ct++) {
        int col = ct * 16 + i16;
        float bv = ba[col];
        f32x4 acc = (f32x4){bv, bv, bv, bv};
        #pragma unroll
        for (int s = 0; s < K / 32; s++) {
            bf16x8 b = *(const bf16x8*)&waT[(size_t)col * K + s * 32 + q * 8];
            acc = __builtin_amdgcn_mfma_f32_16x16x32_bf16(aA[s], b, acc, 0, 0, 0);
        }
        #pragma unroll
        for (int r = 0; r < 4; r++) {
            float v = acc[r] > 0.f ? acc[r] : 0.f;
            myHid[(q * 4 + r) * HSTR + col] = f2bf(v);
        }
    }
    __syncthreads();

    // ---- layer B: [16 x 128] @ wbT -> relu -> sOut (f32 LDS) ----
    bf16x8 aB[4];
    #pragma unroll
    for (int s = 0; s < 4; s++)
        aB[s] = *(const bf16x8*)&myHid[i16 * HSTR + s * 32 + q * 8];
    #pragma unroll
    for (int ct = 0; ct < 8; ct++) {
        int col = ct * 16 + i16;
        float bv = bb[col];
        f32x4 acc = (f32x4){bv, bv, bv, bv};
        #pragma unroll
        for (int s = 0; s < 4; s++) {
            bf16x8 b = *(const bf16x8*)&wbT[(size_t)col * HID + s * 32 + q * 8];
            acc = __builtin_amdgcn_mfma_f32_16x16x32_bf16(aB[s], b, acc, 0, 0, 0);
        }
        #pragma unroll
        for (int r = 0; r < 4; r++) {
            float v = acc[r] > 0.f ? acc[r] : 0.f;
            sOut[(w * 16 + q * 4 + r) * OSTR + col] = v;
        }
    }
    __syncthreads();

    // ---- epilogue ----
    if (POOL) {
        if (t < HID) {
            float* out = (float*)outv;
            float acc = 0.f;
            int curg = batch[blk0];
            for (int row = 0; row < 64; row++) {
                int node = blk0 + row;
                if (node >= N_NODES) break;
                int g = batch[node];
                if (g != curg) {
                    atomicAdd(&out[curg * HID + t], acc * inv_cnt[curg]);
                    acc = 0.f; curg = g;
                }
                acc += sOut[row * OSTR + t];
            }
            atomicAdd(&out[curg * HID + t], acc * inv_cnt[curg]);
        }
    } else {
        unsigned short* hout = (unsigned short*)outv;
        for (int idx = t; idx < 64 * 16; idx += 256) {
            int row = idx >> 4, ch = idx & 15;   // ch = 16B chunk (8 bf16)
            int node = blk0 + row;
            if (node < N_NODES) {
                float4 f0 = *(const float4*)&sOut[row * OSTR + ch * 8];
                float4 f1 = *(const float4*)&sOut[row * OSTR + ch * 8 + 4];
                uint4 u;
                u.x = (unsigned)f2bf(f0.x) | ((unsigned)f2bf(f0.y) << 16);
                u.y = (unsigned)f2bf(f0.z) | ((unsigned)f2bf(f0.w) << 16);
                u.z = (unsigned)f2bf(f1.x) | ((unsigned)f2bf(f1.y) << 16);
                u.w = (unsigned)f2bf(f1.z) | ((unsigned)f2bf(f1.w) << 16);
                *(uint4*)&hout[(size_t)node * HID + ch * 8] = u;
            }
        }
    }
}

extern "C" void kernel_launch(void* const* d_in, const int* in_sizes, int n_in,
                              void* d_out, int out_size, void* d_ws, size_t ws_size,
                              hipStream_t stream) {
    const float* x    = (const float*)d_in[0];
    const int*   ei   = (const int*)d_in[1];
    const float* ea   = (const float*)d_in[2];
    const int*   batch= (const int*)d_in[3];
    const float* el1w = (const float*)d_in[4];
    const float* el1b = (const float*)d_in[5];
    const float* w1a  = (const float*)d_in[6];
    const float* b1a  = (const float*)d_in[7];
    const float* w1b  = (const float*)d_in[8];
    const float* b1b  = (const float*)d_in[9];
    const float* el2w = (const float*)d_in[10];
    const float* el2b = (const float*)d_in[11];
    const float* w2a  = (const float*)d_in[12];
    const float* b2a  = (const float*)d_in[13];
    const float* w2b  = (const float*)d_in[14];
    const float* b2b  = (const float*)d_in[15];
    float* out = (float*)d_out;

    // workspace layout (16B-aligned sections)
    uint2* edata    = (uint2*)d_ws;                        // [N*CAP] 8B records  25.6 MB
    float* inv_cnt  = (float*)(edata + (size_t)N_NODES * CAP);  // [64] f32 (+pad to 8192)
    int*   deg      = (int*)(inv_cnt + N_GRAPHS * HID);    // [N]  (inv_cnt uses 64 of 8192 slots)
    // ints after edata: 8192 + 50000 = 58192 (16B multiple)
    unsigned short* hbf  = (unsigned short*)((char*)inv_cnt + (size_t)58192 * 4);  // bf16 [N,HID]
    unsigned short* sgbuf= hbf + (size_t)N_NODES * HID;  // bf16 [N_PAD, 128] (layer1 uses stride 64)
    unsigned short* waT1 = sgbuf + (size_t)N_PAD * HID;  // bf16 [128, 64]
    unsigned short* wbT1 = waT1 + HID * IN_CH;           // bf16 [128, 128]
    unsigned short* waT2 = wbT1 + HID * HID;             // bf16 [128, 128]
    unsigned short* wbT2 = waT2 + HID * HID;             // bf16 [128, 128]
    unsigned short* xbf  = wbT2 + HID * HID;             // bf16 [N, 64]

    // ---- prep: zero deg+out, inv_cnt, transposes, x->bf16 ----
    prep_kernel<<<(N_NODES * IN_CH) / 256, 256, 0, stream>>>(
        x, w1a, w1b, w2a, w2b, batch, xbf, waT1, wbT1, waT2, wbT2, deg, out, inv_cnt);
    // ---- edge build: 1 edge/thread, fixed-capacity buckets ----
    build_kernel<<<(N_EDGES + 255) / 256, 256, 0, stream>>>(ei, ea, deg, edata);

    // ---- layer 1: edge-parallel gather -> sg ; MFMA MLP -> hbf (bf16) ----
    gather64_kernel<<<N_NODES / 4, 256, 0, stream>>>(
        xbf, edata, deg, el1w, el1b, sgbuf);
    mlp_mfma_kernel<IN_CH, false><<<N_PAD / 64, 256, 0, stream>>>(
        sgbuf, waT1, b1a, wbT1, b1b, hbf, nullptr, nullptr);

    // ---- layer 2: edge-parallel gather ; MFMA MLP + fused mean ----
    gather128_kernel<<<N_NODES / 4, 256, 0, stream>>>(
        hbf, edata, deg, el2w, el2b, sgbuf);
    mlp_mfma_kernel<HID, true><<<N_PAD / 64, 256, 0, stream>>>(
        sgbuf, waT2, b2a, wbT2, b2b, out, batch, inv_cnt);
}

// Round 8
// 264.076 us; speedup vs baseline: 1.0623x; 1.0623x over previous
//
#include <hip/hip_runtime.h>

#define N_NODES 50000
#define N_EDGES 600000
#define N_PAD 50048        // N rounded up to 64 (mlp tiles)
#define IN_CH 64
#define HID 128
#define N_GRAPHS 64
#define CAP 64             // per-node edge-slot capacity (max degree ~28 for this input)
#define CAP_SHIFT 6

typedef __attribute__((ext_vector_type(8))) short bf16x8;
typedef __attribute__((ext_vector_type(4))) float f32x4;

// ---- bf16 helpers (manual, RNE) ----
__device__ __forceinline__ float bf2f(unsigned short u) {
    union { unsigned int i; float f; } v; v.i = ((unsigned int)u) << 16; return v.f;
}
__device__ __forceinline__ unsigned short f2bf(float f) {
    union { float f; unsigned int i; } v; v.f = f;
    unsigned int u = v.i;
    return (unsigned short)((u + 0x7FFFu + ((u >> 16) & 1u)) >> 16);
}

// 8B edge record: x = src(u16) | a0(bf16)<<16 ; y = a1(bf16) | a2(bf16)<<16

// ===========================================================================
// prep kernel: zero deg + OUT, 4 weight transposes, x->bf16, inv_cnt[64]
// (R6-proven).
// ===========================================================================
__global__ void prep_kernel(const float* __restrict__ x,
                            const float* __restrict__ w1a, const float* __restrict__ w1b,
                            const float* __restrict__ w2a, const float* __restrict__ w2b,
                            const int* __restrict__ batch,
                            unsigned short* __restrict__ xbf,
                            unsigned short* __restrict__ waT1, unsigned short* __restrict__ wbT1,
                            unsigned short* __restrict__ waT2, unsigned short* __restrict__ wbT2,
                            int* __restrict__ deg, float* __restrict__ out,
                            float* __restrict__ inv_cnt) {
    int i = blockIdx.x * blockDim.x + threadIdx.x;
    if (i < N_NODES * IN_CH) xbf[i] = f2bf(x[i]);
    if (i < N_NODES) deg[i] = 0;
    if (i < N_GRAPHS * HID) out[i] = 0.f;
    if (i < N_GRAPHS) {                  // per-graph 1/count (sorted batch)
        int g = i;
        int lo = 0, hi = N_NODES;
        while (lo < hi) { int mid = (lo + hi) >> 1; if (batch[mid] < g) lo = mid + 1; else hi = mid; }
        int start = lo;
        lo = 0; hi = N_NODES;
        while (lo < hi) { int mid = (lo + hi) >> 1; if (batch[mid] <= g) lo = mid + 1; else hi = mid; }
        float c = (float)(lo - start);
        inv_cnt[g] = 1.0f / (c > 1.0f ? c : 1.0f);
    }
    if (i < IN_CH * HID) {               // w1a is [64,128]
        int k = i / HID, n = i % HID;
        waT1[n * IN_CH + k] = f2bf(w1a[i]);
    }
    if (i < HID * HID) {                 // the three [128,128] weights
        int k = i / HID, n = i % HID;
        wbT1[n * HID + k] = f2bf(w1b[i]);
        waT2[n * HID + k] = f2bf(w2a[i]);
        wbT2[n * HID + k] = f2bf(w2b[i]);
    }
}

// ===========================================================================
// Single-pass edge build: 1 edge/thread, fixed-capacity buckets (R2-proven).
// ===========================================================================
__global__ void build_kernel(const int* __restrict__ ei,
                             const float* __restrict__ ea,
                             int* __restrict__ deg,
                             uint2* __restrict__ edata) {
    int i = blockIdx.x * blockDim.x + threadIdx.x;
    if (i >= N_EDGES) return;
    int s = ei[i];
    int d = ei[N_EDGES + i];
    float a0 = ea[3 * (size_t)i], a1 = ea[3 * (size_t)i + 1], a2 = ea[3 * (size_t)i + 2];
    int p = atomicAdd(&deg[d], 1);
    if (p < CAP)
        edata[((size_t)d << CAP_SHIFT) + p] =
            make_uint2((unsigned)s | ((unsigned)f2bf(a0) << 16),
                       (unsigned)f2bf(a1) | ((unsigned)f2bf(a2) << 16));
}

// ===========================================================================
// R8 gather64: edge-parallel lane map (R7) + 4-DEEP BATCHED LOADS. Wave =
// 16 ch-groups x 4 edge slots; per batch, 4 edata loads issue together, then
// 4 row loads together -> 2 latency stages cover 16 edges (avg deg 12: ONE
// batch per node). All indices <= 63 in-bucket; invalid slots predicated
// out of the accumulate only.
// ===========================================================================
__global__ __launch_bounds__(256)
void gather64_kernel(const unsigned short* __restrict__ xin,  // bf16 [N,64]
                     const uint2* __restrict__ edata,
                     const int* __restrict__ deg,
                     const float* __restrict__ elw,  // [3, 64]
                     const float* __restrict__ elb,  // [64]
                     unsigned short* __restrict__ sg) {  // bf16 [N, 64]
    const int t = threadIdx.x;
    const int w = t >> 6, l = t & 63;
    const int s = l >> 4;            // edge slot 0..3
    const int c = 4 * (l & 15);      // channel base (4 channels/lane)
    const int node = blockIdx.x * 4 + w;

    const float4 w0 = *(const float4*)&elw[c];
    const float4 w1 = *(const float4*)&elw[64 + c];
    const float4 w2 = *(const float4*)&elw[128 + c];
    const float4 eb = *(const float4*)&elb[c];

    float a0 = 0.f, a1 = 0.f, a2 = 0.f, a3 = 0.f;
    int dn = deg[node]; if (dn > CAP) dn = CAP;
    const int base = node << CAP_SHIFT;

    auto acc1 = [&](uint2 e, uint2 r, bool valid) {
        float A0 = bf2f((unsigned short)(e.x >> 16));
        float A1 = bf2f((unsigned short)(e.y & 0xFFFF));
        float A2 = bf2f((unsigned short)(e.y >> 16));
        float m0 = bf2f((unsigned short)(r.x & 0xFFFF)) + A0 * w0.x + A1 * w1.x + A2 * w2.x + eb.x;
        float m1 = bf2f((unsigned short)(r.x >> 16))    + A0 * w0.y + A1 * w1.y + A2 * w2.y + eb.y;
        float m2 = bf2f((unsigned short)(r.y & 0xFFFF)) + A0 * w0.z + A1 * w1.z + A2 * w2.z + eb.z;
        float m3 = bf2f((unsigned short)(r.y >> 16))    + A0 * w0.w + A1 * w1.w + A2 * w2.w + eb.w;
        m0 = m0 > 0.f ? m0 : 0.f;  m1 = m1 > 0.f ? m1 : 0.f;
        m2 = m2 > 0.f ? m2 : 0.f;  m3 = m3 > 0.f ? m3 : 0.f;
        a0 += valid ? m0 : 0.f;  a1 += valid ? m1 : 0.f;
        a2 += valid ? m2 : 0.f;  a3 += valid ? m3 : 0.f;
    };

    for (int j0 = 0; j0 < dn; j0 += 16) {
        // stage 1: 4 independent edata loads (indices <= j0+12+3 <= 63)
        uint2 e0 = edata[base + j0 + s];
        uint2 e1 = edata[base + j0 + 4 + s];
        uint2 e2 = edata[base + j0 + 8 + s];
        uint2 e3 = edata[base + j0 + 12 + s];
        bool v0 = (j0 + s) < dn,      v1 = (j0 + 4 + s) < dn;
        bool v2 = (j0 + 8 + s) < dn,  v3 = (j0 + 12 + s) < dn;
        unsigned s0 = v0 ? (e0.x & 0xFFFFu) : 0u;
        unsigned s1 = v1 ? (e1.x & 0xFFFFu) : 0u;
        unsigned s2 = v2 ? (e2.x & 0xFFFFu) : 0u;
        unsigned s3 = v3 ? (e3.x & 0xFFFFu) : 0u;
        // stage 2: 4 independent row loads
        uint2 r0 = *(const uint2*)&xin[(size_t)s0 * 64 + c];
        uint2 r1 = *(const uint2*)&xin[(size_t)s1 * 64 + c];
        uint2 r2 = *(const uint2*)&xin[(size_t)s2 * 64 + c];
        uint2 r3 = *(const uint2*)&xin[(size_t)s3 * 64 + c];
        acc1(e0, r0, v0); acc1(e1, r1, v1); acc1(e2, r2, v2); acc1(e3, r3, v3);
    }
    // combine the 4 edge slots (lanes l, l^16, l^32, l^48 share channels)
    a0 += __shfl_xor(a0, 16); a0 += __shfl_xor(a0, 32);
    a1 += __shfl_xor(a1, 16); a1 += __shfl_xor(a1, 32);
    a2 += __shfl_xor(a2, 16); a2 += __shfl_xor(a2, 32);
    a3 += __shfl_xor(a3, 16); a3 += __shfl_xor(a3, 32);
    if (s == 0) {
        uint2 sv = *(const uint2*)&xin[(size_t)node * 64 + c];   // self row
        a0 += bf2f((unsigned short)(sv.x & 0xFFFF));
        a1 += bf2f((unsigned short)(sv.x >> 16));
        a2 += bf2f((unsigned short)(sv.y & 0xFFFF));
        a3 += bf2f((unsigned short)(sv.y >> 16));
        uint2 o;
        o.x = (unsigned)f2bf(a0) | ((unsigned)f2bf(a1) << 16);
        o.y = (unsigned)f2bf(a2) | ((unsigned)f2bf(a3) << 16);
        *(uint2*)&sg[(size_t)node * 64 + c] = o;
    }
}

// ===========================================================================
// R8 gather128: edge-parallel (32 ch-groups x 2 slots) + 4-deep batching.
// Per batch: 4 edata + 4 row loads issue in 2 stages, covering 8 edges.
// ===========================================================================
__global__ __launch_bounds__(256)
void gather128_kernel(const unsigned short* __restrict__ xin,  // bf16 [N,128]
                      const uint2* __restrict__ edata,
                      const int* __restrict__ deg,
                      const float* __restrict__ elw,  // [3, 128]
                      const float* __restrict__ elb,  // [128]
                      unsigned short* __restrict__ sg) {  // bf16 [N, 128]
    const int t = threadIdx.x;
    const int w = t >> 6, l = t & 63;
    const int s = l >> 5;            // edge slot 0..1
    const int c = 4 * (l & 31);      // channel base (4 channels/lane)
    const int node = blockIdx.x * 4 + w;

    const float4 w0 = *(const float4*)&elw[c];
    const float4 w1 = *(const float4*)&elw[HID + c];
    const float4 w2 = *(const float4*)&elw[2 * HID + c];
    const float4 eb = *(const float4*)&elb[c];

    float a0 = 0.f, a1 = 0.f, a2 = 0.f, a3 = 0.f;
    int dn = deg[node]; if (dn > CAP) dn = CAP;
    const int base = node << CAP_SHIFT;

    auto acc1 = [&](uint2 e, uint2 r, bool valid) {
        float A0 = bf2f((unsigned short)(e.x >> 16));
        float A1 = bf2f((unsigned short)(e.y & 0xFFFF));
        float A2 = bf2f((unsigned short)(e.y >> 16));
        float m0 = bf2f((unsigned short)(r.x & 0xFFFF)) + A0 * w0.x + A1 * w1.x + A2 * w2.x + eb.x;
        float m1 = bf2f((unsigned short)(r.x >> 16))    + A0 * w0.y + A1 * w1.y + A2 * w2.y + eb.y;
        float m2 = bf2f((unsigned short)(r.y & 0xFFFF)) + A0 * w0.z + A1 * w1.z + A2 * w2.z + eb.z;
        float m3 = bf2f((unsigned short)(r.y >> 16))    + A0 * w0.w + A1 * w1.w + A2 * w2.w + eb.w;
        m0 = m0 > 0.f ? m0 : 0.f;  m1 = m1 > 0.f ? m1 : 0.f;
        m2 = m2 > 0.f ? m2 : 0.f;  m3 = m3 > 0.f ? m3 : 0.f;
        a0 += valid ? m0 : 0.f;  a1 += valid ? m1 : 0.f;
        a2 += valid ? m2 : 0.f;  a3 += valid ? m3 : 0.f;
    };

    for (int j0 = 0; j0 < dn; j0 += 8) {
        // stage 1: 4 independent edata loads (indices <= j0+6+1 <= 63)
        uint2 e0 = edata[base + j0 + s];
        uint2 e1 = edata[base + j0 + 2 + s];
        uint2 e2 = edata[base + j0 + 4 + s];
        uint2 e3 = edata[base + j0 + 6 + s];
        bool v0 = (j0 + s) < dn,      v1 = (j0 + 2 + s) < dn;
        bool v2 = (j0 + 4 + s) < dn,  v3 = (j0 + 6 + s) < dn;
        unsigned s0 = v0 ? (e0.x & 0xFFFFu) : 0u;
        unsigned s1 = v1 ? (e1.x & 0xFFFFu) : 0u;
        unsigned s2 = v2 ? (e2.x & 0xFFFFu) : 0u;
        unsigned s3 = v3 ? (e3.x & 0xFFFFu) : 0u;
        // stage 2: 4 independent row loads
        uint2 r0 = *(const uint2*)&xin[(size_t)s0 * 128 + c];
        uint2 r1 = *(const uint2*)&xin[(size_t)s1 * 128 + c];
        uint2 r2 = *(const uint2*)&xin[(size_t)s2 * 128 + c];
        uint2 r3 = *(const uint2*)&xin[(size_t)s3 * 128 + c];
        acc1(e0, r0, v0); acc1(e1, r1, v1); acc1(e2, r2, v2); acc1(e3, r3, v3);
    }
    // combine the 2 edge slots (lanes l and l^32 share channels)
    a0 += __shfl_xor(a0, 32);
    a1 += __shfl_xor(a1, 32);
    a2 += __shfl_xor(a2, 32);
    a3 += __shfl_xor(a3, 32);
    if (s == 0) {
        uint2 sv = *(const uint2*)&xin[(size_t)node * 128 + c];  // self row
        a0 += bf2f((unsigned short)(sv.x & 0xFFFF));
        a1 += bf2f((unsigned short)(sv.x >> 16));
        a2 += bf2f((unsigned short)(sv.y & 0xFFFF));
        a3 += bf2f((unsigned short)(sv.y >> 16));
        uint2 o;
        o.x = (unsigned)f2bf(a0) | ((unsigned)f2bf(a1) << 16);
        o.y = (unsigned)f2bf(a2) | ((unsigned)f2bf(a3) << 16);
        *(uint2*)&sg[(size_t)node * 128 + c] = o;
    }
}

// ===========================================================================
// Standalone MFMA MLP — R12-proven body; R6 fused-mean POOL epilogue.
// ===========================================================================
template <int K, bool POOL>
__global__ __launch_bounds__(256)
void mlp_mfma_kernel(const unsigned short* __restrict__ sg,   // bf16 [N_PAD, K]
                     const unsigned short* __restrict__ waT,  // bf16 [HID, K]
                     const float* __restrict__ ba,
                     const unsigned short* __restrict__ wbT,  // bf16 [HID, HID]
                     const float* __restrict__ bb,
                     void* __restrict__ outv,                 // bf16 h or f32 out
                     const int* __restrict__ batch,
                     const float* __restrict__ inv_cnt) {
    constexpr int HSTR = 136;      // shorts
    constexpr int OSTR = HID + 4;  // f32
    __shared__ __align__(16) unsigned short sHid[4][16 * HSTR];  // 17.4 KB
    __shared__ __align__(16) float sOut[64 * OSTR];              // 33.8 KB
    const int t = threadIdx.x;
    const int w = t >> 6, l = t & 63;
    const int i16 = l & 15, q = l >> 4;
    const int blk0 = blockIdx.x * 64;
    const int row0 = blk0 + w * 16;   // this wave's 16 rows

    // ---- layer A: [16 x K] @ waT -> relu -> own LDS buffer ----
    bf16x8 aA[K / 32];
    #pragma unroll
    for (int s = 0; s < K / 32; s++)
        aA[s] = *(const bf16x8*)&sg[(size_t)(row0 + i16) * K + s * 32 + q * 8];
    unsigned short* myHid = sHid[w];
    #pragma unroll
    for (int ct = 0; ct < 8; ct++) {
        int col = ct * 16 + i16;
        float bv = ba[col];
        f32x4 acc = (f32x4){bv, bv, bv, bv};
        #pragma unroll
        for (int s = 0; s < K / 32; s++) {
            bf16x8 b = *(const bf16x8*)&waT[(size_t)col * K + s * 32 + q * 8];
            acc = __builtin_amdgcn_mfma_f32_16x16x32_bf16(aA[s], b, acc, 0, 0, 0);
        }
        #pragma unroll
        for (int r = 0; r < 4; r++) {
            float v = acc[r] > 0.f ? acc[r] : 0.f;
            myHid[(q * 4 + r) * HSTR + col] = f2bf(v);
        }
    }
    __syncthreads();

    // ---- layer B: [16 x 128] @ wbT -> relu -> sOut (f32 LDS) ----
    bf16x8 aB[4];
    #pragma unroll
    for (int s = 0; s < 4; s++)
        aB[s] = *(const bf16x8*)&myHid[i16 * HSTR + s * 32 + q * 8];
    #pragma unroll
    for (int ct = 0; ct < 8; ct++) {
        int col = ct * 16 + i16;
        float bv = bb[col];
        f32x4 acc = (f32x4){bv, bv, bv, bv};
        #pragma unroll
        for (int s = 0; s < 4; s++) {
            bf16x8 b = *(const bf16x8*)&wbT[(size_t)col * HID + s * 32 + q * 8];
            acc = __builtin_amdgcn_mfma_f32_16x16x32_bf16(aB[s], b, acc, 0, 0, 0);
        }
        #pragma unroll
        for (int r = 0; r < 4; r++) {
            float v = acc[r] > 0.f ? acc[r] : 0.f;
            sOut[(w * 16 + q * 4 + r) * OSTR + col] = v;
        }
    }
    __syncthreads();

    // ---- epilogue ----
    if (POOL) {
        if (t < HID) {
            float* out = (float*)outv;
            float acc = 0.f;
            int curg = batch[blk0];
            for (int row = 0; row < 64; row++) {
                int node = blk0 + row;
                if (node >= N_NODES) break;
                int g = batch[node];
                if (g != curg) {
                    atomicAdd(&out[curg * HID + t], acc * inv_cnt[curg]);
                    acc = 0.f; curg = g;
                }
                acc += sOut[row * OSTR + t];
            }
            atomicAdd(&out[curg * HID + t], acc * inv_cnt[curg]);
        }
    } else {
        unsigned short* hout = (unsigned short*)outv;
        for (int idx = t; idx < 64 * 16; idx += 256) {
            int row = idx >> 4, ch = idx & 15;   // ch = 16B chunk (8 bf16)
            int node = blk0 + row;
            if (node < N_NODES) {
                float4 f0 = *(const float4*)&sOut[row * OSTR + ch * 8];
                float4 f1 = *(const float4*)&sOut[row * OSTR + ch * 8 + 4];
                uint4 u;
                u.x = (unsigned)f2bf(f0.x) | ((unsigned)f2bf(f0.y) << 16);
                u.y = (unsigned)f2bf(f0.z) | ((unsigned)f2bf(f0.w) << 16);
                u.z = (unsigned)f2bf(f1.x) | ((unsigned)f2bf(f1.y) << 16);
                u.w = (unsigned)f2bf(f1.z) | ((unsigned)f2bf(f1.w) << 16);
                *(uint4*)&hout[(size_t)node * HID + ch * 8] = u;
            }
        }
    }
}

extern "C" void kernel_launch(void* const* d_in, const int* in_sizes, int n_in,
                              void* d_out, int out_size, void* d_ws, size_t ws_size,
                              hipStream_t stream) {
    const float* x    = (const float*)d_in[0];
    const int*   ei   = (const int*)d_in[1];
    const float* ea   = (const float*)d_in[2];
    const int*   batch= (const int*)d_in[3];
    const float* el1w = (const float*)d_in[4];
    const float* el1b = (const float*)d_in[5];
    const float* w1a  = (const float*)d_in[6];
    const float* b1a  = (const float*)d_in[7];
    const float* w1b  = (const float*)d_in[8];
    const float* b1b  = (const float*)d_in[9];
    const float* el2w = (const float*)d_in[10];
    const float* el2b = (const float*)d_in[11];
    const float* w2a  = (const float*)d_in[12];
    const float* b2a  = (const float*)d_in[13];
    const float* w2b  = (const float*)d_in[14];
    const float* b2b  = (const float*)d_in[15];
    float* out = (float*)d_out;

    // workspace layout (16B-aligned sections)
    uint2* edata    = (uint2*)d_ws;                        // [N*CAP] 8B records  25.6 MB
    float* inv_cnt  = (float*)(edata + (size_t)N_NODES * CAP);  // [64] f32 (+pad to 8192)
    int*   deg      = (int*)(inv_cnt + N_GRAPHS * HID);    // [N]  (inv_cnt uses 64 of 8192 slots)
    // ints after edata: 8192 + 50000 = 58192 (16B multiple)
    unsigned short* hbf  = (unsigned short*)((char*)inv_cnt + (size_t)58192 * 4);  // bf16 [N,HID]
    unsigned short* sgbuf= hbf + (size_t)N_NODES * HID;  // bf16 [N_PAD, 128] (layer1 uses stride 64)
    unsigned short* waT1 = sgbuf + (size_t)N_PAD * HID;  // bf16 [128, 64]
    unsigned short* wbT1 = waT1 + HID * IN_CH;           // bf16 [128, 128]
    unsigned short* waT2 = wbT1 + HID * HID;             // bf16 [128, 128]
    unsigned short* wbT2 = waT2 + HID * HID;             // bf16 [128, 128]
    unsigned short* xbf  = wbT2 + HID * HID;             // bf16 [N, 64]

    // ---- prep: zero deg+out, inv_cnt, transposes, x->bf16 ----
    prep_kernel<<<(N_NODES * IN_CH) / 256, 256, 0, stream>>>(
        x, w1a, w1b, w2a, w2b, batch, xbf, waT1, wbT1, waT2, wbT2, deg, out, inv_cnt);
    // ---- edge build: 1 edge/thread, fixed-capacity buckets ----
    build_kernel<<<(N_EDGES + 255) / 256, 256, 0, stream>>>(ei, ea, deg, edata);

    // ---- layer 1: edge-parallel batched gather -> sg ; MFMA MLP -> hbf ----
    gather64_kernel<<<N_NODES / 4, 256, 0, stream>>>(
        xbf, edata, deg, el1w, el1b, sgbuf);
    mlp_mfma_kernel<IN_CH, false><<<N_PAD / 64, 256, 0, stream>>>(
        sgbuf, waT1, b1a, wbT1, b1b, hbf, nullptr, nullptr);

    // ---- layer 2: edge-parallel batched gather ; MFMA MLP + fused mean ----
    gather128_kernel<<<N_NODES / 4, 256, 0, stream>>>(
        hbf, edata, deg, el2w, el2b, sgbuf);
    mlp_mfma_kernel<HID, true><<<N_PAD / 64, 256, 0, stream>>>(
        sgbuf, waT2, b2a, wbT2, b2b, out, batch, inv_cnt);
}

// Round 9
// 259.971 us; speedup vs baseline: 1.0790x; 1.0158x over previous
//
#include <hip/hip_runtime.h>

#define N_NODES 50000
#define N_EDGES 600000
#define N_PAD 50048        // N rounded up to 64 (mlp tiles)
#define IN_CH 64
#define HID 128
#define N_GRAPHS 64
#define CAP 64             // per-node edge-slot capacity (max degree ~28 for this input)
#define CAP_SHIFT 6
#define BUILD_BLOCKS ((N_EDGES + 255) / 256)          // 2344
#define PREP_BLOCKS  ((N_NODES * IN_CH / 4) / 256)    // 3125

typedef __attribute__((ext_vector_type(8))) short bf16x8;
typedef __attribute__((ext_vector_type(4))) float f32x4;

// ---- bf16 helpers (manual, RNE) ----
__device__ __forceinline__ float bf2f(unsigned short u) {
    union { unsigned int i; float f; } v; v.i = ((unsigned int)u) << 16; return v.f;
}
__device__ __forceinline__ unsigned short f2bf(float f) {
    union { float f; unsigned int i; } v; v.f = f;
    unsigned int u = v.i;
    return (unsigned short)((u + 0x7FFFu + ((u >> 16) & 1u)) >> 16);
}

// 8B edge record: x = src(u16) | a0(bf16)<<16 ; y = a1(bf16) | a2(bf16)<<16

// ===========================================================================
// R9: FUSED prep+build. deg is zeroed by a preceding hipMemsetAsync; the two
// roles are otherwise independent, so one kernel runs them in disjoint block
// ranges — build (latency/atomic-bound) first so its chains start earliest,
// prep (BW-bound, now float4-vectorized) fills the CUs behind it. Serial
// prep+build becomes ~max(prep,build).
// ===========================================================================
__global__ void prep_build_kernel(const float* __restrict__ x,
                                  const int* __restrict__ ei,
                                  const float* __restrict__ ea,
                                  const int* __restrict__ batch,
                                  const float* __restrict__ w1a, const float* __restrict__ w1b,
                                  const float* __restrict__ w2a, const float* __restrict__ w2b,
                                  unsigned short* __restrict__ xbf,
                                  unsigned short* __restrict__ waT1, unsigned short* __restrict__ wbT1,
                                  unsigned short* __restrict__ waT2, unsigned short* __restrict__ wbT2,
                                  int* __restrict__ deg, uint2* __restrict__ edata,
                                  float* __restrict__ out, float* __restrict__ inv_cnt) {
    const int b = blockIdx.x;
    if (b < BUILD_BLOCKS) {
        // ---------------- build role: 1 edge/thread (R2-proven) ----------
        int i = b * 256 + threadIdx.x;
        if (i >= N_EDGES) return;
        int s = ei[i];
        int d = ei[N_EDGES + i];
        float a0 = ea[3 * (size_t)i], a1 = ea[3 * (size_t)i + 1], a2 = ea[3 * (size_t)i + 2];
        int p = atomicAdd(&deg[d], 1);
        if (p < CAP)
            edata[((size_t)d << CAP_SHIFT) + p] =
                make_uint2((unsigned)s | ((unsigned)f2bf(a0) << 16),
                           (unsigned)f2bf(a1) | ((unsigned)f2bf(a2) << 16));
    } else {
        // ---------------- prep role ------------------------------------
        int i = (b - BUILD_BLOCKS) * 256 + threadIdx.x;
        if (i < N_NODES * IN_CH / 4) {       // x -> bf16, 4 floats/thread
            float4 v = ((const float4*)x)[i];
            uint2 o;
            o.x = (unsigned)f2bf(v.x) | ((unsigned)f2bf(v.y) << 16);
            o.y = (unsigned)f2bf(v.z) | ((unsigned)f2bf(v.w) << 16);
            ((uint2*)xbf)[i] = o;
        }
        if (i < N_GRAPHS * HID) out[i] = 0.f;
        if (i < N_GRAPHS) {                  // per-graph 1/count (sorted batch)
            int g = i;
            int lo = 0, hi = N_NODES;
            while (lo < hi) { int mid = (lo + hi) >> 1; if (batch[mid] < g) lo = mid + 1; else hi = mid; }
            int start = lo;
            lo = 0; hi = N_NODES;
            while (lo < hi) { int mid = (lo + hi) >> 1; if (batch[mid] <= g) lo = mid + 1; else hi = mid; }
            float c = (float)(lo - start);
            inv_cnt[g] = 1.0f / (c > 1.0f ? c : 1.0f);
        }
        if (i < IN_CH * HID) {               // w1a is [64,128]
            int k = i / HID, n = i % HID;
            waT1[n * IN_CH + k] = f2bf(w1a[i]);
        }
        if (i < HID * HID) {                 // the three [128,128] weights
            int k = i / HID, n = i % HID;
            wbT1[n * HID + k] = f2bf(w1b[i]);
            waT2[n * HID + k] = f2bf(w2a[i]);
            wbT2[n * HID + k] = f2bf(w2b[i]);
        }
    }
}

// ===========================================================================
// R8 gather64 (unchanged): edge-parallel lane map + 4-deep batched loads.
// ===========================================================================
__global__ __launch_bounds__(256)
void gather64_kernel(const unsigned short* __restrict__ xin,  // bf16 [N,64]
                     const uint2* __restrict__ edata,
                     const int* __restrict__ deg,
                     const float* __restrict__ elw,  // [3, 64]
                     const float* __restrict__ elb,  // [64]
                     unsigned short* __restrict__ sg) {  // bf16 [N, 64]
    const int t = threadIdx.x;
    const int w = t >> 6, l = t & 63;
    const int s = l >> 4;            // edge slot 0..3
    const int c = 4 * (l & 15);      // channel base (4 channels/lane)
    const int node = blockIdx.x * 4 + w;

    const float4 w0 = *(const float4*)&elw[c];
    const float4 w1 = *(const float4*)&elw[64 + c];
    const float4 w2 = *(const float4*)&elw[128 + c];
    const float4 eb = *(const float4*)&elb[c];

    float a0 = 0.f, a1 = 0.f, a2 = 0.f, a3 = 0.f;
    int dn = deg[node]; if (dn > CAP) dn = CAP;
    const int base = node << CAP_SHIFT;

    auto acc1 = [&](uint2 e, uint2 r, bool valid) {
        float A0 = bf2f((unsigned short)(e.x >> 16));
        float A1 = bf2f((unsigned short)(e.y & 0xFFFF));
        float A2 = bf2f((unsigned short)(e.y >> 16));
        float m0 = bf2f((unsigned short)(r.x & 0xFFFF)) + A0 * w0.x + A1 * w1.x + A2 * w2.x + eb.x;
        float m1 = bf2f((unsigned short)(r.x >> 16))    + A0 * w0.y + A1 * w1.y + A2 * w2.y + eb.y;
        float m2 = bf2f((unsigned short)(r.y & 0xFFFF)) + A0 * w0.z + A1 * w1.z + A2 * w2.z + eb.z;
        float m3 = bf2f((unsigned short)(r.y >> 16))    + A0 * w0.w + A1 * w1.w + A2 * w2.w + eb.w;
        m0 = m0 > 0.f ? m0 : 0.f;  m1 = m1 > 0.f ? m1 : 0.f;
        m2 = m2 > 0.f ? m2 : 0.f;  m3 = m3 > 0.f ? m3 : 0.f;
        a0 += valid ? m0 : 0.f;  a1 += valid ? m1 : 0.f;
        a2 += valid ? m2 : 0.f;  a3 += valid ? m3 : 0.f;
    };

    for (int j0 = 0; j0 < dn; j0 += 16) {
        uint2 e0 = edata[base + j0 + s];
        uint2 e1 = edata[base + j0 + 4 + s];
        uint2 e2 = edata[base + j0 + 8 + s];
        uint2 e3 = edata[base + j0 + 12 + s];
        bool v0 = (j0 + s) < dn,      v1 = (j0 + 4 + s) < dn;
        bool v2 = (j0 + 8 + s) < dn,  v3 = (j0 + 12 + s) < dn;
        unsigned s0 = v0 ? (e0.x & 0xFFFFu) : 0u;
        unsigned s1 = v1 ? (e1.x & 0xFFFFu) : 0u;
        unsigned s2 = v2 ? (e2.x & 0xFFFFu) : 0u;
        unsigned s3 = v3 ? (e3.x & 0xFFFFu) : 0u;
        uint2 r0 = *(const uint2*)&xin[(size_t)s0 * 64 + c];
        uint2 r1 = *(const uint2*)&xin[(size_t)s1 * 64 + c];
        uint2 r2 = *(const uint2*)&xin[(size_t)s2 * 64 + c];
        uint2 r3 = *(const uint2*)&xin[(size_t)s3 * 64 + c];
        acc1(e0, r0, v0); acc1(e1, r1, v1); acc1(e2, r2, v2); acc1(e3, r3, v3);
    }
    a0 += __shfl_xor(a0, 16); a0 += __shfl_xor(a0, 32);
    a1 += __shfl_xor(a1, 16); a1 += __shfl_xor(a1, 32);
    a2 += __shfl_xor(a2, 16); a2 += __shfl_xor(a2, 32);
    a3 += __shfl_xor(a3, 16); a3 += __shfl_xor(a3, 32);
    if (s == 0) {
        uint2 sv = *(const uint2*)&xin[(size_t)node * 64 + c];   // self row
        a0 += bf2f((unsigned short)(sv.x & 0xFFFF));
        a1 += bf2f((unsigned short)(sv.x >> 16));
        a2 += bf2f((unsigned short)(sv.y & 0xFFFF));
        a3 += bf2f((unsigned short)(sv.y >> 16));
        uint2 o;
        o.x = (unsigned)f2bf(a0) | ((unsigned)f2bf(a1) << 16);
        o.y = (unsigned)f2bf(a2) | ((unsigned)f2bf(a3) << 16);
        *(uint2*)&sg[(size_t)node * 64 + c] = o;
    }
}

// ===========================================================================
// R8 gather128 (unchanged): edge-parallel (32 ch-groups x 2 slots) + 4-deep
// batching.
// ===========================================================================
__global__ __launch_bounds__(256)
void gather128_kernel(const unsigned short* __restrict__ xin,  // bf16 [N,128]
                      const uint2* __restrict__ edata,
                      const int* __restrict__ deg,
                      const float* __restrict__ elw,  // [3, 128]
                      const float* __restrict__ elb,  // [128]
                      unsigned short* __restrict__ sg) {  // bf16 [N, 128]
    const int t = threadIdx.x;
    const int w = t >> 6, l = t & 63;
    const int s = l >> 5;            // edge slot 0..1
    const int c = 4 * (l & 31);      // channel base (4 channels/lane)
    const int node = blockIdx.x * 4 + w;

    const float4 w0 = *(const float4*)&elw[c];
    const float4 w1 = *(const float4*)&elw[HID + c];
    const float4 w2 = *(const float4*)&elw[2 * HID + c];
    const float4 eb = *(const float4*)&elb[c];

    float a0 = 0.f, a1 = 0.f, a2 = 0.f, a3 = 0.f;
    int dn = deg[node]; if (dn > CAP) dn = CAP;
    const int base = node << CAP_SHIFT;

    auto acc1 = [&](uint2 e, uint2 r, bool valid) {
        float A0 = bf2f((unsigned short)(e.x >> 16));
        float A1 = bf2f((unsigned short)(e.y & 0xFFFF));
        float A2 = bf2f((unsigned short)(e.y >> 16));
        float m0 = bf2f((unsigned short)(r.x & 0xFFFF)) + A0 * w0.x + A1 * w1.x + A2 * w2.x + eb.x;
        float m1 = bf2f((unsigned short)(r.x >> 16))    + A0 * w0.y + A1 * w1.y + A2 * w2.y + eb.y;
        float m2 = bf2f((unsigned short)(r.y & 0xFFFF)) + A0 * w0.z + A1 * w1.z + A2 * w2.z + eb.z;
        float m3 = bf2f((unsigned short)(r.y >> 16))    + A0 * w0.w + A1 * w1.w + A2 * w2.w + eb.w;
        m0 = m0 > 0.f ? m0 : 0.f;  m1 = m1 > 0.f ? m1 : 0.f;
        m2 = m2 > 0.f ? m2 : 0.f;  m3 = m3 > 0.f ? m3 : 0.f;
        a0 += valid ? m0 : 0.f;  a1 += valid ? m1 : 0.f;
        a2 += valid ? m2 : 0.f;  a3 += valid ? m3 : 0.f;
    };

    for (int j0 = 0; j0 < dn; j0 += 8) {
        uint2 e0 = edata[base + j0 + s];
        uint2 e1 = edata[base + j0 + 2 + s];
        uint2 e2 = edata[base + j0 + 4 + s];
        uint2 e3 = edata[base + j0 + 6 + s];
        bool v0 = (j0 + s) < dn,      v1 = (j0 + 2 + s) < dn;
        bool v2 = (j0 + 4 + s) < dn,  v3 = (j0 + 6 + s) < dn;
        unsigned s0 = v0 ? (e0.x & 0xFFFFu) : 0u;
        unsigned s1 = v1 ? (e1.x & 0xFFFFu) : 0u;
        unsigned s2 = v2 ? (e2.x & 0xFFFFu) : 0u;
        unsigned s3 = v3 ? (e3.x & 0xFFFFu) : 0u;
        uint2 r0 = *(const uint2*)&xin[(size_t)s0 * 128 + c];
        uint2 r1 = *(const uint2*)&xin[(size_t)s1 * 128 + c];
        uint2 r2 = *(const uint2*)&xin[(size_t)s2 * 128 + c];
        uint2 r3 = *(const uint2*)&xin[(size_t)s3 * 128 + c];
        acc1(e0, r0, v0); acc1(e1, r1, v1); acc1(e2, r2, v2); acc1(e3, r3, v3);
    }
    a0 += __shfl_xor(a0, 32);
    a1 += __shfl_xor(a1, 32);
    a2 += __shfl_xor(a2, 32);
    a3 += __shfl_xor(a3, 32);
    if (s == 0) {
        uint2 sv = *(const uint2*)&xin[(size_t)node * 128 + c];  // self row
        a0 += bf2f((unsigned short)(sv.x & 0xFFFF));
        a1 += bf2f((unsigned short)(sv.x >> 16));
        a2 += bf2f((unsigned short)(sv.y & 0xFFFF));
        a3 += bf2f((unsigned short)(sv.y >> 16));
        uint2 o;
        o.x = (unsigned)f2bf(a0) | ((unsigned)f2bf(a1) << 16);
        o.y = (unsigned)f2bf(a2) | ((unsigned)f2bf(a3) << 16);
        *(uint2*)&sg[(size_t)node * 128 + c] = o;
    }
}

// ===========================================================================
// Standalone MFMA MLP — R12-proven body; R6 fused-mean POOL epilogue.
// ===========================================================================
template <int K, bool POOL>
__global__ __launch_bounds__(256)
void mlp_mfma_kernel(const unsigned short* __restrict__ sg,   // bf16 [N_PAD, K]
                     const unsigned short* __restrict__ waT,  // bf16 [HID, K]
                     const float* __restrict__ ba,
                     const unsigned short* __restrict__ wbT,  // bf16 [HID, HID]
                     const float* __restrict__ bb,
                     void* __restrict__ outv,                 // bf16 h or f32 out
                     const int* __restrict__ batch,
                     const float* __restrict__ inv_cnt) {
    constexpr int HSTR = 136;      // shorts
    constexpr int OSTR = HID + 4;  // f32
    __shared__ __align__(16) unsigned short sHid[4][16 * HSTR];  // 17.4 KB
    __shared__ __align__(16) float sOut[64 * OSTR];              // 33.8 KB
    const int t = threadIdx.x;
    const int w = t >> 6, l = t & 63;
    const int i16 = l & 15, q = l >> 4;
    const int blk0 = blockIdx.x * 64;
    const int row0 = blk0 + w * 16;   // this wave's 16 rows

    // ---- layer A: [16 x K] @ waT -> relu -> own LDS buffer ----
    bf16x8 aA[K / 32];
    #pragma unroll
    for (int s = 0; s < K / 32; s++)
        aA[s] = *(const bf16x8*)&sg[(size_t)(row0 + i16) * K + s * 32 + q * 8];
    unsigned short* myHid = sHid[w];
    #pragma unroll
    for (int ct = 0; ct < 8; ct++) {
        int col = ct * 16 + i16;
        float bv = ba[col];
        f32x4 acc = (f32x4){bv, bv, bv, bv};
        #pragma unroll
        for (int s = 0; s < K / 32; s++) {
            bf16x8 b = *(const bf16x8*)&waT[(size_t)col * K + s * 32 + q * 8];
            acc = __builtin_amdgcn_mfma_f32_16x16x32_bf16(aA[s], b, acc, 0, 0, 0);
        }
        #pragma unroll
        for (int r = 0; r < 4; r++) {
            float v = acc[r] > 0.f ? acc[r] : 0.f;
            myHid[(q * 4 + r) * HSTR + col] = f2bf(v);
        }
    }
    __syncthreads();

    // ---- layer B: [16 x 128] @ wbT -> relu -> sOut (f32 LDS) ----
    bf16x8 aB[4];
    #pragma unroll
    for (int s = 0; s < 4; s++)
        aB[s] = *(const bf16x8*)&myHid[i16 * HSTR + s * 32 + q * 8];
    #pragma unroll
    for (int ct = 0; ct < 8; ct++) {
        int col = ct * 16 + i16;
        float bv = bb[col];
        f32x4 acc = (f32x4){bv, bv, bv, bv};
        #pragma unroll
        for (int s = 0; s < 4; s++) {
            bf16x8 b = *(const bf16x8*)&wbT[(size_t)col * HID + s * 32 + q * 8];
            acc = __builtin_amdgcn_mfma_f32_16x16x32_bf16(aB[s], b, acc, 0, 0, 0);
        }
        #pragma unroll
        for (int r = 0; r < 4; r++) {
            float v = acc[r] > 0.f ? acc[r] : 0.f;
            sOut[(w * 16 + q * 4 + r) * OSTR + col] = v;
        }
    }
    __syncthreads();

    // ---- epilogue ----
    if (POOL) {
        if (t < HID) {
            float* out = (float*)outv;
            float acc = 0.f;
            int curg = batch[blk0];
            for (int row = 0; row < 64; row++) {
                int node = blk0 + row;
                if (node >= N_NODES) break;
                int g = batch[node];
                if (g != curg) {
                    atomicAdd(&out[curg * HID + t], acc * inv_cnt[curg]);
                    acc = 0.f; curg = g;
                }
                acc += sOut[row * OSTR + t];
            }
            atomicAdd(&out[curg * HID + t], acc * inv_cnt[curg]);
        }
    } else {
        unsigned short* hout = (unsigned short*)outv;
        for (int idx = t; idx < 64 * 16; idx += 256) {
            int row = idx >> 4, ch = idx & 15;   // ch = 16B chunk (8 bf16)
            int node = blk0 + row;
            if (node < N_NODES) {
                float4 f0 = *(const float4*)&sOut[row * OSTR + ch * 8];
                float4 f1 = *(const float4*)&sOut[row * OSTR + ch * 8 + 4];
                uint4 u;
                u.x = (unsigned)f2bf(f0.x) | ((unsigned)f2bf(f0.y) << 16);
                u.y = (unsigned)f2bf(f0.z) | ((unsigned)f2bf(f0.w) << 16);
                u.z = (unsigned)f2bf(f1.x) | ((unsigned)f2bf(f1.y) << 16);
                u.w = (unsigned)f2bf(f1.z) | ((unsigned)f2bf(f1.w) << 16);
                *(uint4*)&hout[(size_t)node * HID + ch * 8] = u;
            }
        }
    }
}

extern "C" void kernel_launch(void* const* d_in, const int* in_sizes, int n_in,
                              void* d_out, int out_size, void* d_ws, size_t ws_size,
                              hipStream_t stream) {
    const float* x    = (const float*)d_in[0];
    const int*   ei   = (const int*)d_in[1];
    const float* ea   = (const float*)d_in[2];
    const int*   batch= (const int*)d_in[3];
    const float* el1w = (const float*)d_in[4];
    const float* el1b = (const float*)d_in[5];
    const float* w1a  = (const float*)d_in[6];
    const float* b1a  = (const float*)d_in[7];
    const float* w1b  = (const float*)d_in[8];
    const float* b1b  = (const float*)d_in[9];
    const float* el2w = (const float*)d_in[10];
    const float* el2b = (const float*)d_in[11];
    const float* w2a  = (const float*)d_in[12];
    const float* b2a  = (const float*)d_in[13];
    const float* w2b  = (const float*)d_in[14];
    const float* b2b  = (const float*)d_in[15];
    float* out = (float*)d_out;

    // workspace layout (16B-aligned sections)
    uint2* edata    = (uint2*)d_ws;                        // [N*CAP] 8B records  25.6 MB
    float* inv_cnt  = (float*)(edata + (size_t)N_NODES * CAP);  // [64] f32 (+pad to 8192)
    int*   deg      = (int*)(inv_cnt + N_GRAPHS * HID);    // [N]
    // ints after edata: 8192 + 50000 = 58192 (16B multiple)
    unsigned short* hbf  = (unsigned short*)((char*)inv_cnt + (size_t)58192 * 4);  // bf16 [N,HID]
    unsigned short* sgbuf= hbf + (size_t)N_NODES * HID;  // bf16 [N_PAD, 128] (layer1 uses stride 64)
    unsigned short* waT1 = sgbuf + (size_t)N_PAD * HID;  // bf16 [128, 64]
    unsigned short* wbT1 = waT1 + HID * IN_CH;           // bf16 [128, 128]
    unsigned short* waT2 = wbT1 + HID * HID;             // bf16 [128, 128]
    unsigned short* wbT2 = waT2 + HID * HID;             // bf16 [128, 128]
    unsigned short* xbf  = wbT2 + HID * HID;             // bf16 [N, 64]

    // ---- deg zero (tiny fill) then fused prep+build (roles overlap) ----
    hipMemsetAsync(deg, 0, (size_t)N_NODES * sizeof(int), stream);
    prep_build_kernel<<<BUILD_BLOCKS + PREP_BLOCKS, 256, 0, stream>>>(
        x, ei, ea, batch, w1a, w1b, w2a, w2b,
        xbf, waT1, wbT1, waT2, wbT2, deg, edata, out, inv_cnt);

    // ---- layer 1: edge-parallel batched gather -> sg ; MFMA MLP -> hbf ----
    gather64_kernel<<<N_NODES / 4, 256, 0, stream>>>(
        xbf, edata, deg, el1w, el1b, sgbuf);
    mlp_mfma_kernel<IN_CH, false><<<N_PAD / 64, 256, 0, stream>>>(
        sgbuf, waT1, b1a, wbT1, b1b, hbf, nullptr, nullptr);

    // ---- layer 2: edge-parallel batched gather ; MFMA MLP + fused mean ----
    gather128_kernel<<<N_NODES / 4, 256, 0, stream>>>(
        hbf, edata, deg, el2w, el2b, sgbuf);
    mlp_mfma_kernel<HID, true><<<N_PAD / 64, 256, 0, stream>>>(
        sgbuf, waT2, b2a, wbT2, b2b, out, batch, inv_cnt);
}